// Round 8
// baseline (190.694 us; speedup 1.0000x reference)
//
#include <hip/hip_runtime.h>
#include <hip/hip_fp16.h>

#define NN 100000
#define NE 1600000

typedef short s8v  __attribute__((ext_vector_type(8)));    // 8 bf16 = 4 VGPRs
typedef float f4   __attribute__((ext_vector_type(4)));
typedef float f16v __attribute__((ext_vector_type(16)));   // 32x32 MFMA accumulator

// ---------- dtype helpers ----------
__device__ __forceinline__ unsigned short f2b(float f) {   // fp32 -> bf16 RNE (prep only)
    unsigned int u = __float_as_uint(f);
    return (unsigned short)((u + 0x7fffu + ((u >> 16) & 1u)) >> 16);
}
__device__ __forceinline__ unsigned int cvtpk(float lo, float hi) {  // 2xf32 -> packed bf16 (RNE)
    unsigned int r;
    asm("v_cvt_pk_bf16_f32 %0, %1, %2" : "=v"(r) : "v"(lo), "v"(hi));
    return r;
}

// Inter-layer exchange for 32x32x16 chains (proven R2/R5/R6/R7).
// swap(a, b):  r[0] = {lo: own a | hi: partner-lo b}   -> j = 0..1 word
//              r[1] = {lo: partner-hi a | hi: own b}   -> j = 4..5 word
template<int BASE>
__device__ __forceinline__ s8v interleave8(f16v C) {
    unsigned a0 = cvtpk(fmaxf(C[BASE + 0], 0.f), fmaxf(C[BASE + 1], 0.f)); // rel rows 0,1 (+4h5)
    unsigned a1 = cvtpk(fmaxf(C[BASE + 2], 0.f), fmaxf(C[BASE + 3], 0.f)); // rel rows 2,3
    unsigned b0 = cvtpk(fmaxf(C[BASE + 4], 0.f), fmaxf(C[BASE + 5], 0.f)); // rel rows 8,9
    unsigned b1 = cvtpk(fmaxf(C[BASE + 6], 0.f), fmaxf(C[BASE + 7], 0.f)); // rel rows 10,11
    auto r0 = __builtin_amdgcn_permlane32_swap((int)a0, (int)b0, false, false);
    auto r1 = __builtin_amdgcn_permlane32_swap((int)a1, (int)b1, false, false);
    uint4 q;
    q.x = (unsigned)r0[0];
    q.y = (unsigned)r1[0];
    q.z = (unsigned)r0[1];
    q.w = (unsigned)r1[1];
    return __builtin_bit_cast(s8v, q);
}

// ---------- workspace layout (float index) ----------
// pk replica0 @0      [100000 __half2] | pk replica1 @100000 [100000 __half2]   (R7 fallback path)
// phi b1 @204868[64] | phi w2 @204932[64] | phi b2 @204996[1]
// phi fragW0 @205000 (2048 bf16) | phi fragW1 @206024 (4096 bf16)
// flags @208100 | gam fragW0 @208104 (1024 bf16) | gam fragW1 @209128 (4096 bf16)
// gam b1 @211176[64] | gam w2 @211240[64] | gam b2 @211304[1]
// mode1: x-bf16 mirror @212000 (400000 floats, ends 612000)
// mode2: per-XCD f32 accumulators @212000: [xcd][node][2] = 8*200000 floats, ends 1812000

__global__ __launch_bounds__(256) void prep(
    const float* __restrict__ pW0, const float* __restrict__ pb0,
    const float* __restrict__ pW1, const float* __restrict__ pb1,
    const float* __restrict__ pW2, const float* __restrict__ pb2,
    const float* __restrict__ gW0, const float* __restrict__ gb0,
    const float* __restrict__ gW1, const float* __restrict__ gb1,
    const float* __restrict__ gW2, const float* __restrict__ gb2,
    const int* __restrict__ ei, const float* __restrict__ xin,
    float* __restrict__ ws, int mode)
{
    // ---- zero accumulators (all blocks) ----
    if (mode == 2) {
        for (int i = blockIdx.x * 256 + threadIdx.x; i < 1600000; i += gridDim.x * 256)
            ws[212000 + i] = 0.0f;
    } else {
        for (int i = blockIdx.x * 256 + threadIdx.x; i < 200000; i += gridDim.x * 256)
            ws[i] = 0.0f;
    }

    // ---- pack x -> bf16 mirror (mode 1 only) ----
    if (mode == 1) {
        uint4* xbu = (uint4*)(ws + 212000);
        for (int i = blockIdx.x * 256 + threadIdx.x; i < NN; i += gridDim.x * 256) {
            f4 a = *(const f4*)(xin + i * 8);
            f4 b = *(const f4*)(xin + i * 8 + 4);
            uint4 o;
            o.x = cvtpk(a[0], a[1]); o.y = cvtpk(a[2], a[3]);
            o.z = cvtpk(b[0], b[1]); o.w = cvtpk(b[2], b[3]);
            xbu[i] = o;
        }
    }

    // ---- sniff edge-index width (last block only) ----
    if (blockIdx.x == gridDim.x - 1) {
        __shared__ int s_zero;
        if (threadIdx.x == 0) s_zero = 0;
        __syncthreads();
        int zero = 0;
        for (int i = threadIdx.x; i < 1024; i += 256)
            if (ei[2 * i + 1] == 0) zero++;      // int64 high words all zero
        atomicAdd(&s_zero, zero);
        __syncthreads();
        if (threadIdx.x == 0) ((int*)(ws + 208100))[0] = (s_zero > 512) ? 1 : 0;
        return;
    }

    // ---- weight staging ----
    int t = blockIdx.x * 256 + threadIdx.x;
    if (t < 64)        ws[204868 + t] = pb1[t];
    else if (t < 128)  ws[204932 + t - 64] = pW2[t - 64];
    else if (t == 128) ws[204996] = pb2[0];
    else if (t >= 256 && t < 2304) {            // phi fragW0 (2048): bias folded at k=18
        int fe = t - 256;
        int j = fe & 7, ln = (fe >> 3) & 63, ts = fe >> 9;
        int tt = ts >> 1, s = ts & 1;
        int k = s * 16 + (ln >> 5) * 8 + j;
        int n = tt * 32 + (ln & 31);
        float v = (k < 18) ? pW0[k * 64 + n] : ((k == 18) ? pb0[n] : 0.0f);
        ((unsigned short*)(ws + 205000))[fe] = f2b(v);
    }
    else if (t >= 2304 && t < 6400) {           // phi fragW1 (4096)
        int fe = t - 2304;
        int j = fe & 7, ln = (fe >> 3) & 63, f = fe >> 9;
        int tt = f >> 2, s2 = f & 3;
        int k = s2 * 16 + (ln >> 5) * 8 + j;
        int n = tt * 32 + (ln & 31);
        ((unsigned short*)(ws + 206024))[fe] = f2b(pW1[k * 64 + n]);
    }
    else if (t >= 6400 && t < 7424) {           // gam fragW0 (1024): bias folded at k=9
        int fe = t - 6400;
        int j = fe & 7, ln = (fe >> 3) & 63, tt = fe >> 9;
        int k = (ln >> 5) * 8 + j;
        int n = tt * 32 + (ln & 31);
        float v = (k < 9) ? gW0[k * 64 + n] : ((k == 9) ? gb0[n] : 0.0f);
        ((unsigned short*)(ws + 208104))[fe] = f2b(v);
    }
    else if (t >= 7424 && t < 11520) {          // gam fragW1 (4096)
        int fe = t - 7424;
        int j = fe & 7, ln = (fe >> 3) & 63, f = fe >> 9;
        int tt = f >> 2, s2 = f & 3;
        int k = s2 * 16 + (ln >> 5) * 8 + j;
        int n = tt * 32 + (ln & 31);
        ((unsigned short*)(ws + 209128))[fe] = f2b(gW1[k * 64 + n]);
    }
    else if (t >= 11520 && t < 11584) ws[211176 + t - 11520] = gb1[t - 11520];
    else if (t >= 11584 && t < 11648) ws[211240 + t - 11584] = gW2[t - 11584];
    else if (t == 11648) ws[211304] = gb2[0];
}

// ---------- shared phi body macro'd via inline function ----------
struct PhiRegs {
    s8v wA0[4], wA1[8];
    f16v B1a, B1b;
    f4 w2v[8];
    float phib2;
};
__device__ __forceinline__ void load_phi(const float* ws, int lane, int h5, PhiRegs& P) {
    const unsigned short* fw0 = (const unsigned short*)(ws + 205000);
    const unsigned short* fw1 = (const unsigned short*)(ws + 206024);
#pragma unroll
    for (int t = 0; t < 4; t++) P.wA0[t] = *(const s8v*)(fw0 + (t * 64 + lane) * 8);
#pragma unroll
    for (int f = 0; f < 8; f++) P.wA1[f] = *(const s8v*)(fw1 + (f * 64 + lane) * 8);
    const float* b1p = ws + 204868;
    const float* w2p = ws + 204932;
#pragma unroll
    for (int g = 0; g < 4; g++) {
        f4 ba = *(const f4*)(b1p + g * 8 + h5 * 4);
        f4 bb = *(const f4*)(b1p + 32 + g * 8 + h5 * 4);
#pragma unroll
        for (int i = 0; i < 4; i++) { P.B1a[g * 4 + i] = ba[i]; P.B1b[g * 4 + i] = bb[i]; }
        P.w2v[g]     = *(const f4*)(w2p + g * 8 + h5 * 4);
        P.w2v[4 + g] = *(const f4*)(w2p + 32 + g * 8 + h5 * 4);
    }
    P.phib2 = ws[204996];
}
// phi MLP on one edge-tile worth of B-fragments; returns msg in all lanes
__device__ __forceinline__ float phi_eval(const PhiRegs& P, s8v bf0, s8v bf1) {
    f16v zz;
#pragma unroll
    for (int r = 0; r < 16; r++) zz[r] = 0.f;
    f16v C1 = __builtin_amdgcn_mfma_f32_32x32x16_bf16(P.wA0[0], bf0, zz, 0, 0, 0);
    C1 = __builtin_amdgcn_mfma_f32_32x32x16_bf16(P.wA0[1], bf1, C1, 0, 0, 0);
    s8v g0 = interleave8<0>(C1);
    s8v g1 = interleave8<8>(C1);
    C1 = __builtin_amdgcn_mfma_f32_32x32x16_bf16(P.wA0[2], bf0, zz, 0, 0, 0);
    C1 = __builtin_amdgcn_mfma_f32_32x32x16_bf16(P.wA0[3], bf1, C1, 0, 0, 0);
    s8v g2 = interleave8<0>(C1);
    s8v g3 = interleave8<8>(C1);

    f16v C2a = __builtin_amdgcn_mfma_f32_32x32x16_bf16(P.wA1[0], g0, P.B1a, 0, 0, 0);
    C2a = __builtin_amdgcn_mfma_f32_32x32x16_bf16(P.wA1[1], g1, C2a, 0, 0, 0);
    C2a = __builtin_amdgcn_mfma_f32_32x32x16_bf16(P.wA1[2], g2, C2a, 0, 0, 0);
    C2a = __builtin_amdgcn_mfma_f32_32x32x16_bf16(P.wA1[3], g3, C2a, 0, 0, 0);
    f16v C2b = __builtin_amdgcn_mfma_f32_32x32x16_bf16(P.wA1[4], g0, P.B1b, 0, 0, 0);
    C2b = __builtin_amdgcn_mfma_f32_32x32x16_bf16(P.wA1[5], g1, C2b, 0, 0, 0);
    C2b = __builtin_amdgcn_mfma_f32_32x32x16_bf16(P.wA1[6], g2, C2b, 0, 0, 0);
    C2b = __builtin_amdgcn_mfma_f32_32x32x16_bf16(P.wA1[7], g3, C2b, 0, 0, 0);

    float pm = 0.f;
#pragma unroll
    for (int r = 0; r < 16; r++) {
        pm = fmaf(fmaxf(C2a[r], 0.f), P.w2v[r >> 2][r & 3], pm);
        pm = fmaf(fmaxf(C2b[r], 0.f), P.w2v[4 + (r >> 2)][r & 3], pm);
    }
    int pi = __builtin_bit_cast(int, pm);
    auto rr = __builtin_amdgcn_permlane32_swap(pi, pi, false, false);
    return __builtin_bit_cast(float, (int)rr[0])
         + __builtin_bit_cast(float, (int)rr[1]) + P.phib2;
}

// ---------- edge kernel A (fallback, R5-proven): device-scope f16x2 atomics to pk0 ----------
__global__ __launch_bounds__(256) void edge_mfma(
    const float* __restrict__ x, const float* __restrict__ pos,
    const int* __restrict__ ei, float* __restrict__ ws,
    const int* __restrict__ flags)
{
    const int lane = threadIdx.x & 63;
    const int c5   = lane & 31;
    const int h5   = lane >> 5;
    const int fidx = flags[0];
    PhiRegs P; load_phi(ws, lane, h5, P);

    __half2* pk = (__half2*)ws;
    const float2* pf = (const float2*)pos;
    const int gw    = blockIdx.x * 4 + (threadIdx.x >> 6);
    const int nwave = gridDim.x * 4;

    for (int tile = gw; tile < NE / 32; tile += nwave) {
        int eg = tile * 32 + c5;
        int src, dst;
        if (fidx) { src = __builtin_nontemporal_load(ei + 2 * eg);
                    dst = __builtin_nontemporal_load(ei + 2 * (NE + eg)); }
        else      { src = __builtin_nontemporal_load(ei + eg);
                    dst = __builtin_nontemporal_load(ei + NE + eg); }
        if ((unsigned)src >= (unsigned)NN) src = 0;
        if ((unsigned)dst >= (unsigned)NN) dst = 0;

        int sel = h5 ? src : dst;
        f4 xa = *(const f4*)(x + sel * 8);
        f4 xb = *(const f4*)(x + sel * 8 + 4);
        float dpx = 0.f, dpy = 0.f, onev = 0.f;
        if (!h5) {
            float2 ps = pf[src], pd = pf[dst];
            dpx = ps.x - pd.x; dpy = ps.y - pd.y; onev = 1.0f;
        }
        uint4 q0;
        q0.x = cvtpk(xa[0], xa[1]); q0.y = cvtpk(xa[2], xa[3]);
        q0.z = cvtpk(xb[0], xb[1]); q0.w = cvtpk(xb[2], xb[3]);
        uint4 q1;
        q1.x = cvtpk(dpx, dpy); q1.y = cvtpk(onev, 0.f); q1.z = 0u; q1.w = 0u;

        float msg = phi_eval(P, __builtin_bit_cast(s8v, q0), __builtin_bit_cast(s8v, q1));

        if (!h5)
            unsafeAtomicAdd(pk + dst, __halves2half2(__float2half(msg), __float2half(1.0f)));
    }
}

// ---------- edge kernel C (mode 2): XCD-local f32 atomics into per-XCD replicas ----------
__global__ __launch_bounds__(256) void edge_xcd(
    const float* __restrict__ x, const float* __restrict__ pos,
    const int* __restrict__ ei, float* __restrict__ ws,
    const int* __restrict__ flags)
{
    const int lane = threadIdx.x & 63;
    const int c5   = lane & 31;
    const int h5   = lane >> 5;
    const int fidx = flags[0];
    PhiRegs P; load_phi(ws, lane, h5, P);

    int xcd;
    asm("s_getreg_b32 %0, hwreg(HW_REG_XCC_ID)" : "=s"(xcd));
    xcd &= 7;
    float* acc = ws + 212000 + xcd * 200000;     // [node][2] : sum, cnt (this XCD only)

    const float2* pf = (const float2*)pos;
    const int gw    = blockIdx.x * 4 + (threadIdx.x >> 6);
    const int nwave = gridDim.x * 4;

    for (int tile = gw; tile < NE / 32; tile += nwave) {
        int eg = tile * 32 + c5;
        int src, dst;
        if (fidx) { src = __builtin_nontemporal_load(ei + 2 * eg);
                    dst = __builtin_nontemporal_load(ei + 2 * (NE + eg)); }
        else      { src = __builtin_nontemporal_load(ei + eg);
                    dst = __builtin_nontemporal_load(ei + NE + eg); }
        if ((unsigned)src >= (unsigned)NN) src = 0;
        if ((unsigned)dst >= (unsigned)NN) dst = 0;

        int sel = h5 ? src : dst;
        f4 xa = *(const f4*)(x + sel * 8);
        f4 xb = *(const f4*)(x + sel * 8 + 4);
        float dpx = 0.f, dpy = 0.f, onev = 0.f;
        if (!h5) {
            float2 ps = pf[src], pd = pf[dst];
            dpx = ps.x - pd.x; dpy = ps.y - pd.y; onev = 1.0f;
        }
        uint4 q0;
        q0.x = cvtpk(xa[0], xa[1]); q0.y = cvtpk(xa[2], xa[3]);
        q0.z = cvtpk(xb[0], xb[1]); q0.w = cvtpk(xb[2], xb[3]);
        uint4 q1;
        q1.x = cvtpk(dpx, dpy); q1.y = cvtpk(onev, 0.f); q1.z = 0u; q1.w = 0u;

        float msg = phi_eval(P, __builtin_bit_cast(s8v, q0), __builtin_bit_cast(s8v, q1));

        // XCD-local accumulation: all atomics to this replica come from THIS XCD
        // (physical XCC_ID), so workgroup-scope (L2-executed, no sc1) is sufficient.
        // h5=0 lanes add msg at [dst][0]; h5=1 lanes add 1.0 at [dst][1].
        float* p = acc + 2 * dst + h5;
        __hip_atomic_fetch_add(p, h5 ? 1.0f : msg,
                               __ATOMIC_RELAXED, __HIP_MEMORY_SCOPE_WORKGROUP);
    }
}

// ---------- node kernel (modes 0/1): sums pk0+pk1 half2 replicas (R7-proven) ----------
__global__ __launch_bounds__(256) void node_mfma(
    const float* __restrict__ x, float* __restrict__ ws,
    float* __restrict__ out)
{
    const int lane = threadIdx.x & 63;
    const int c5   = lane & 31;
    const int h5   = lane >> 5;

    const unsigned short* fw0 = (const unsigned short*)(ws + 208104);
    const unsigned short* fw1 = (const unsigned short*)(ws + 209128);
    s8v wA0[2], wA1[8];
#pragma unroll
    for (int t = 0; t < 2; t++) wA0[t] = *(const s8v*)(fw0 + (t * 64 + lane) * 8);
#pragma unroll
    for (int f = 0; f < 8; f++) wA1[f] = *(const s8v*)(fw1 + (f * 64 + lane) * 8);

    const float* b1p = ws + 211176;
    const float* w2p = ws + 211240;
    f16v B1a, B1b;
    f4 w2v[8];
#pragma unroll
    for (int g = 0; g < 4; g++) {
        f4 ba = *(const f4*)(b1p + g * 8 + h5 * 4);
        f4 bb = *(const f4*)(b1p + 32 + g * 8 + h5 * 4);
#pragma unroll
        for (int i = 0; i < 4; i++) { B1a[g * 4 + i] = ba[i]; B1b[g * 4 + i] = bb[i]; }
        w2v[g]     = *(const f4*)(w2p + g * 8 + h5 * 4);
        w2v[4 + g] = *(const f4*)(w2p + 32 + g * 8 + h5 * 4);
    }
    const float gamb2 = ws[211304];

    f16v zz;
#pragma unroll
    for (int r = 0; r < 16; r++) zz[r] = 0.f;

    const __half2* pk = (const __half2*)ws;
    const int gw    = blockIdx.x * 4 + (threadIdx.x >> 6);
    const int nwave = gridDim.x * 4;

    for (int tile = gw; tile < NN / 32; tile += nwave) {
        int n = tile * 32 + c5;
        f4 xa = {0.f, 0.f, 0.f, 0.f}, xb = {0.f, 0.f, 0.f, 0.f};
        float aggv = 0.f;
        if (!h5) {
            xa = *(const f4*)(x + n * 8);
            xb = *(const f4*)(x + n * 8 + 4);
        } else {
            __half2 pc0 = pk[n];
            __half2 pc1 = pk[n + 100000];
            float s  = __half2float(pc0.x) + __half2float(pc1.x);
            float ct = __half2float(pc0.y) + __half2float(pc1.y);
            aggv = s / fmaxf(ct, 1.0f);
        }
        uint4 q0;
        q0.x = h5 ? cvtpk(aggv, 1.0f) : cvtpk(xa[0], xa[1]);
        q0.y = h5 ? 0u : cvtpk(xa[2], xa[3]);
        q0.z = h5 ? 0u : cvtpk(xb[0], xb[1]);
        q0.w = h5 ? 0u : cvtpk(xb[2], xb[3]);
        s8v bf0 = __builtin_bit_cast(s8v, q0);

        f16v C1 = __builtin_amdgcn_mfma_f32_32x32x16_bf16(wA0[0], bf0, zz, 0, 0, 0);
        s8v g0 = interleave8<0>(C1);
        s8v g1 = interleave8<8>(C1);
        C1 = __builtin_amdgcn_mfma_f32_32x32x16_bf16(wA0[1], bf0, zz, 0, 0, 0);
        s8v g2 = interleave8<0>(C1);
        s8v g3 = interleave8<8>(C1);

        f16v C2a = __builtin_amdgcn_mfma_f32_32x32x16_bf16(wA1[0], g0, B1a, 0, 0, 0);
        C2a = __builtin_amdgcn_mfma_f32_32x32x16_bf16(wA1[1], g1, C2a, 0, 0, 0);
        C2a = __builtin_amdgcn_mfma_f32_32x32x16_bf16(wA1[2], g2, C2a, 0, 0, 0);
        C2a = __builtin_amdgcn_mfma_f32_32x32x16_bf16(wA1[3], g3, C2a, 0, 0, 0);
        f16v C2b = __builtin_amdgcn_mfma_f32_32x32x16_bf16(wA1[4], g0, B1b, 0, 0, 0);
        C2b = __builtin_amdgcn_mfma_f32_32x32x16_bf16(wA1[5], g1, C2b, 0, 0, 0);
        C2b = __builtin_amdgcn_mfma_f32_32x32x16_bf16(wA1[6], g2, C2b, 0, 0, 0);
        C2b = __builtin_amdgcn_mfma_f32_32x32x16_bf16(wA1[7], g3, C2b, 0, 0, 0);

        float pm = 0.f;
#pragma unroll
        for (int r = 0; r < 16; r++) {
            pm = fmaf(fmaxf(C2a[r], 0.f), w2v[r >> 2][r & 3], pm);
            pm = fmaf(fmaxf(C2b[r], 0.f), w2v[4 + (r >> 2)][r & 3], pm);
        }
        int pi = __builtin_bit_cast(int, pm);
        auto rr = __builtin_amdgcn_permlane32_swap(pi, pi, false, false);
        float tot = __builtin_bit_cast(float, (int)rr[0])
                  + __builtin_bit_cast(float, (int)rr[1]);

        if (!h5)
            out[n] = xb[3] + tot + gamb2;
    }
}

// ---------- node kernel (mode 2): sums 8 per-XCD f32 replicas ----------
__global__ __launch_bounds__(256) void node_xcd(
    const float* __restrict__ x, float* __restrict__ ws,
    float* __restrict__ out)
{
    const int lane = threadIdx.x & 63;
    const int c5   = lane & 31;
    const int h5   = lane >> 5;

    const unsigned short* fw0 = (const unsigned short*)(ws + 208104);
    const unsigned short* fw1 = (const unsigned short*)(ws + 209128);
    s8v wA0[2], wA1[8];
#pragma unroll
    for (int t = 0; t < 2; t++) wA0[t] = *(const s8v*)(fw0 + (t * 64 + lane) * 8);
#pragma unroll
    for (int f = 0; f < 8; f++) wA1[f] = *(const s8v*)(fw1 + (f * 64 + lane) * 8);

    const float* b1p = ws + 211176;
    const float* w2p = ws + 211240;
    f16v B1a, B1b;
    f4 w2v[8];
#pragma unroll
    for (int g = 0; g < 4; g++) {
        f4 ba = *(const f4*)(b1p + g * 8 + h5 * 4);
        f4 bb = *(const f4*)(b1p + 32 + g * 8 + h5 * 4);
#pragma unroll
        for (int i = 0; i < 4; i++) { B1a[g * 4 + i] = ba[i]; B1b[g * 4 + i] = bb[i]; }
        w2v[g]     = *(const f4*)(w2p + g * 8 + h5 * 4);
        w2v[4 + g] = *(const f4*)(w2p + 32 + g * 8 + h5 * 4);
    }
    const float gamb2 = ws[211304];

    f16v zz;
#pragma unroll
    for (int r = 0; r < 16; r++) zz[r] = 0.f;

    const int gw    = blockIdx.x * 4 + (threadIdx.x >> 6);
    const int nwave = gridDim.x * 4;

    for (int tile = gw; tile < NN / 32; tile += nwave) {
        int n = tile * 32 + c5;
        f4 xa = {0.f, 0.f, 0.f, 0.f}, xb = {0.f, 0.f, 0.f, 0.f};
        float aggv = 0.f;
        if (!h5) {
            xa = *(const f4*)(x + n * 8);
            xb = *(const f4*)(x + n * 8 + 4);
        } else {
            float s = 0.f, ct = 0.f;
#pragma unroll
            for (int r = 0; r < 8; r++) {
                float2 v = *(const float2*)(ws + 212000 + r * 200000 + 2 * n);
                s += v.x; ct += v.y;
            }
            aggv = s / fmaxf(ct, 1.0f);
        }
        uint4 q0;
        q0.x = h5 ? cvtpk(aggv, 1.0f) : cvtpk(xa[0], xa[1]);
        q0.y = h5 ? 0u : cvtpk(xa[2], xa[3]);
        q0.z = h5 ? 0u : cvtpk(xb[0], xb[1]);
        q0.w = h5 ? 0u : cvtpk(xb[2], xb[3]);
        s8v bf0 = __builtin_bit_cast(s8v, q0);

        f16v C1 = __builtin_amdgcn_mfma_f32_32x32x16_bf16(wA0[0], bf0, zz, 0, 0, 0);
        s8v g0 = interleave8<0>(C1);
        s8v g1 = interleave8<8>(C1);
        C1 = __builtin_amdgcn_mfma_f32_32x32x16_bf16(wA0[1], bf0, zz, 0, 0, 0);
        s8v g2 = interleave8<0>(C1);
        s8v g3 = interleave8<8>(C1);

        f16v C2a = __builtin_amdgcn_mfma_f32_32x32x16_bf16(wA1[0], g0, B1a, 0, 0, 0);
        C2a = __builtin_amdgcn_mfma_f32_32x32x16_bf16(wA1[1], g1, C2a, 0, 0, 0);
        C2a = __builtin_amdgcn_mfma_f32_32x32x16_bf16(wA1[2], g2, C2a, 0, 0, 0);
        C2a = __builtin_amdgcn_mfma_f32_32x32x16_bf16(wA1[3], g3, C2a, 0, 0, 0);
        f16v C2b = __builtin_amdgcn_mfma_f32_32x32x16_bf16(wA1[4], g0, B1b, 0, 0, 0);
        C2b = __builtin_amdgcn_mfma_f32_32x32x16_bf16(wA1[5], g1, C2b, 0, 0, 0);
        C2b = __builtin_amdgcn_mfma_f32_32x32x16_bf16(wA1[6], g2, C2b, 0, 0, 0);
        C2b = __builtin_amdgcn_mfma_f32_32x32x16_bf16(wA1[7], g3, C2b, 0, 0, 0);

        float pm = 0.f;
#pragma unroll
        for (int r = 0; r < 16; r++) {
            pm = fmaf(fmaxf(C2a[r], 0.f), w2v[r >> 2][r & 3], pm);
            pm = fmaf(fmaxf(C2b[r], 0.f), w2v[4 + (r >> 2)][r & 3], pm);
        }
        int pi = __builtin_bit_cast(int, pm);
        auto rr = __builtin_amdgcn_permlane32_swap(pi, pi, false, false);
        float tot = __builtin_bit_cast(float, (int)rr[0])
                  + __builtin_bit_cast(float, (int)rr[1]);

        if (!h5)
            out[n] = xb[3] + tot + gamb2;
    }
}

extern "C" void kernel_launch(void* const* d_in, const int* in_sizes, int n_in,
                              void* d_out, int out_size, void* d_ws, size_t ws_size,
                              hipStream_t stream) {
    const float* x   = (const float*)d_in[0];
    const float* pos = (const float*)d_in[1];
    const int*   ei  = (const int*)d_in[2];

    float* ws    = (float*)d_ws;
    int*   flags = (int*)(ws + 208100);

    const int mode = (ws_size >= 1812000ull * 4ull) ? 2
                   : (ws_size >= 612000ull * 4ull)  ? 0 : 0;
    // mode 2: per-XCD f32 replicas; mode 0: R5 device-atomic path (proven)

    prep<<<256, 256, 0, stream>>>(
        (const float*)d_in[3],  (const float*)d_in[4],  (const float*)d_in[5],
        (const float*)d_in[6],  (const float*)d_in[7],  (const float*)d_in[8],
        (const float*)d_in[9],  (const float*)d_in[10], (const float*)d_in[11],
        (const float*)d_in[12], (const float*)d_in[13], (const float*)d_in[14],
        ei, x, ws, mode);

    if (mode == 2) {
        edge_xcd<<<2048, 256, 0, stream>>>(x, pos, ei, ws, flags);
        node_xcd<<<1024, 256, 0, stream>>>(x, ws, (float*)d_out);
    } else {
        edge_mfma<<<2048, 256, 0, stream>>>(x, pos, ei, ws, flags);
        node_mfma<<<1024, 256, 0, stream>>>(x, ws, (float*)d_out);
    }
}

// Round 9
// 187.521 us; speedup vs baseline: 1.0169x; 1.0169x over previous
//
#include <hip/hip_runtime.h>
#include <hip/hip_fp16.h>

#define NN 100000
#define NE 1600000

typedef short s8v  __attribute__((ext_vector_type(8)));    // 8 bf16 = 4 VGPRs
typedef float f4   __attribute__((ext_vector_type(4)));
typedef float f16v __attribute__((ext_vector_type(16)));   // 32x32 MFMA accumulator

// ---------- dtype helpers ----------
__device__ __forceinline__ unsigned short f2b(float f) {   // fp32 -> bf16 RNE (prep only)
    unsigned int u = __float_as_uint(f);
    return (unsigned short)((u + 0x7fffu + ((u >> 16) & 1u)) >> 16);
}
__device__ __forceinline__ unsigned int cvtpk(float lo, float hi) {  // 2xf32 -> packed bf16 (RNE)
    unsigned int r;
    asm("v_cvt_pk_bf16_f32 %0, %1, %2" : "=v"(r) : "v"(lo), "v"(hi));
    return r;
}

// Inter-layer exchange for 32x32x16 chains (proven R2/R5/R6/R7).
// swap(a, b):  r[0] = {lo: own a | hi: partner-lo b}   -> j = 0..1 word
//              r[1] = {lo: partner-hi a | hi: own b}   -> j = 4..5 word
template<int BASE>
__device__ __forceinline__ s8v interleave8(f16v C) {
    unsigned a0 = cvtpk(fmaxf(C[BASE + 0], 0.f), fmaxf(C[BASE + 1], 0.f));
    unsigned a1 = cvtpk(fmaxf(C[BASE + 2], 0.f), fmaxf(C[BASE + 3], 0.f));
    unsigned b0 = cvtpk(fmaxf(C[BASE + 4], 0.f), fmaxf(C[BASE + 5], 0.f));
    unsigned b1 = cvtpk(fmaxf(C[BASE + 6], 0.f), fmaxf(C[BASE + 7], 0.f));
    auto r0 = __builtin_amdgcn_permlane32_swap((int)a0, (int)b0, false, false);
    auto r1 = __builtin_amdgcn_permlane32_swap((int)a1, (int)b1, false, false);
    uint4 q;
    q.x = (unsigned)r0[0];
    q.y = (unsigned)r1[0];
    q.z = (unsigned)r0[1];
    q.w = (unsigned)r1[1];
    return __builtin_bit_cast(s8v, q);
}

// ---------- workspace layout (float index) ----------
// pk replica0 @0      [100000 __half2] | pk replica1 @100000 [100000 __half2]
// phi b1 @204868[64] | phi w2 @204932[64] | phi b2 @204996[1]
// phi fragW0 @205000 (2048 bf16) | phi fragW1 @206024 (4096 bf16)
// flags @208100 | gam fragW0 @208104 (1024 bf16) | gam fragW1 @209128 (4096 bf16)
// gam b1 @211176[64] | gam w2 @211240[64] | gam b2 @211304[1]
// x-bf16 mirror @212000 (NN uint4 = 400000 floats, ends 612000) -- only if ws big

__global__ __launch_bounds__(256) void prep(
    const float* __restrict__ pW0, const float* __restrict__ pb0,
    const float* __restrict__ pW1, const float* __restrict__ pb1,
    const float* __restrict__ pW2, const float* __restrict__ pb2,
    const float* __restrict__ gW0, const float* __restrict__ gb0,
    const float* __restrict__ gW1, const float* __restrict__ gb1,
    const float* __restrict__ gW2, const float* __restrict__ gb2,
    const int* __restrict__ ei, const float* __restrict__ xin,
    float* __restrict__ ws, int do_x)
{
    // ---- zero BOTH pk replicas (all blocks) ----
    for (int i = blockIdx.x * 256 + threadIdx.x; i < 200000; i += gridDim.x * 256)
        ws[i] = 0.0f;

    // ---- pack x -> bf16 mirror (all blocks; same RNE as the in-loop cvtpk path) ----
    if (do_x) {
        uint4* xbu = (uint4*)(ws + 212000);
        for (int i = blockIdx.x * 256 + threadIdx.x; i < NN; i += gridDim.x * 256) {
            f4 a = *(const f4*)(xin + i * 8);
            f4 b = *(const f4*)(xin + i * 8 + 4);
            uint4 o;
            o.x = cvtpk(a[0], a[1]); o.y = cvtpk(a[2], a[3]);
            o.z = cvtpk(b[0], b[1]); o.w = cvtpk(b[2], b[3]);
            xbu[i] = o;
        }
    }

    // ---- sniff edge-index width (last block only) ----
    if (blockIdx.x == gridDim.x - 1) {
        __shared__ int s_zero;
        if (threadIdx.x == 0) s_zero = 0;
        __syncthreads();
        int zero = 0;
        for (int i = threadIdx.x; i < 1024; i += 256)
            if (ei[2 * i + 1] == 0) zero++;      // int64 high words all zero
        atomicAdd(&s_zero, zero);
        __syncthreads();
        if (threadIdx.x == 0) ((int*)(ws + 208100))[0] = (s_zero > 512) ? 1 : 0;
        return;
    }

    // ---- weight staging ----
    int t = blockIdx.x * 256 + threadIdx.x;
    if (t < 64)        ws[204868 + t] = pb1[t];
    else if (t < 128)  ws[204932 + t - 64] = pW2[t - 64];
    else if (t == 128) ws[204996] = pb2[0];
    else if (t >= 256 && t < 2304) {            // phi fragW0 (2048): bias folded at k=18
        int fe = t - 256;
        int j = fe & 7, ln = (fe >> 3) & 63, ts = fe >> 9;
        int tt = ts >> 1, s = ts & 1;
        int k = s * 16 + (ln >> 5) * 8 + j;
        int n = tt * 32 + (ln & 31);
        float v = (k < 18) ? pW0[k * 64 + n] : ((k == 18) ? pb0[n] : 0.0f);
        ((unsigned short*)(ws + 205000))[fe] = f2b(v);
    }
    else if (t >= 2304 && t < 6400) {           // phi fragW1 (4096)
        int fe = t - 2304;
        int j = fe & 7, ln = (fe >> 3) & 63, f = fe >> 9;
        int tt = f >> 2, s2 = f & 3;
        int k = s2 * 16 + (ln >> 5) * 8 + j;
        int n = tt * 32 + (ln & 31);
        ((unsigned short*)(ws + 206024))[fe] = f2b(pW1[k * 64 + n]);
    }
    else if (t >= 6400 && t < 7424) {           // gam fragW0 (1024): bias folded at k=9
        int fe = t - 6400;
        int j = fe & 7, ln = (fe >> 3) & 63, tt = fe >> 9;
        int k = (ln >> 5) * 8 + j;
        int n = tt * 32 + (ln & 31);
        float v = (k < 9) ? gW0[k * 64 + n] : ((k == 9) ? gb0[n] : 0.0f);
        ((unsigned short*)(ws + 208104))[fe] = f2b(v);
    }
    else if (t >= 7424 && t < 11520) {          // gam fragW1 (4096)
        int fe = t - 7424;
        int j = fe & 7, ln = (fe >> 3) & 63, f = fe >> 9;
        int tt = f >> 2, s2 = f & 3;
        int k = s2 * 16 + (ln >> 5) * 8 + j;
        int n = tt * 32 + (ln & 31);
        ((unsigned short*)(ws + 209128))[fe] = f2b(gW1[k * 64 + n]);
    }
    else if (t >= 11520 && t < 11584) ws[211176 + t - 11520] = gb1[t - 11520];
    else if (t >= 11584 && t < 11648) ws[211240 + t - 11584] = gW2[t - 11584];
    else if (t == 11648) ws[211304] = gb2[0];
}

// ---------- shared phi state + body ----------
struct PhiRegs {
    s8v wA0[4], wA1[8];
    f16v B1a, B1b;
    f4 w2v[8];
    float phib2;
};
__device__ __forceinline__ void load_phi(const float* ws, int lane, int h5, PhiRegs& P) {
    const unsigned short* fw0 = (const unsigned short*)(ws + 205000);
    const unsigned short* fw1 = (const unsigned short*)(ws + 206024);
#pragma unroll
    for (int t = 0; t < 4; t++) P.wA0[t] = *(const s8v*)(fw0 + (t * 64 + lane) * 8);
#pragma unroll
    for (int f = 0; f < 8; f++) P.wA1[f] = *(const s8v*)(fw1 + (f * 64 + lane) * 8);
    const float* b1p = ws + 204868;
    const float* w2p = ws + 204932;
#pragma unroll
    for (int g = 0; g < 4; g++) {
        f4 ba = *(const f4*)(b1p + g * 8 + h5 * 4);
        f4 bb = *(const f4*)(b1p + 32 + g * 8 + h5 * 4);
#pragma unroll
        for (int i = 0; i < 4; i++) { P.B1a[g * 4 + i] = ba[i]; P.B1b[g * 4 + i] = bb[i]; }
        P.w2v[g]     = *(const f4*)(w2p + g * 8 + h5 * 4);
        P.w2v[4 + g] = *(const f4*)(w2p + 32 + g * 8 + h5 * 4);
    }
    P.phib2 = ws[204996];
}
__device__ __forceinline__ float phi_eval(const PhiRegs& P, s8v bf0, s8v bf1) {
    f16v zz;
#pragma unroll
    for (int r = 0; r < 16; r++) zz[r] = 0.f;
    f16v C1 = __builtin_amdgcn_mfma_f32_32x32x16_bf16(P.wA0[0], bf0, zz, 0, 0, 0);
    C1 = __builtin_amdgcn_mfma_f32_32x32x16_bf16(P.wA0[1], bf1, C1, 0, 0, 0);
    s8v g0 = interleave8<0>(C1);
    s8v g1 = interleave8<8>(C1);
    C1 = __builtin_amdgcn_mfma_f32_32x32x16_bf16(P.wA0[2], bf0, zz, 0, 0, 0);
    C1 = __builtin_amdgcn_mfma_f32_32x32x16_bf16(P.wA0[3], bf1, C1, 0, 0, 0);
    s8v g2 = interleave8<0>(C1);
    s8v g3 = interleave8<8>(C1);

    f16v C2a = __builtin_amdgcn_mfma_f32_32x32x16_bf16(P.wA1[0], g0, P.B1a, 0, 0, 0);
    C2a = __builtin_amdgcn_mfma_f32_32x32x16_bf16(P.wA1[1], g1, C2a, 0, 0, 0);
    C2a = __builtin_amdgcn_mfma_f32_32x32x16_bf16(P.wA1[2], g2, C2a, 0, 0, 0);
    C2a = __builtin_amdgcn_mfma_f32_32x32x16_bf16(P.wA1[3], g3, C2a, 0, 0, 0);
    f16v C2b = __builtin_amdgcn_mfma_f32_32x32x16_bf16(P.wA1[4], g0, P.B1b, 0, 0, 0);
    C2b = __builtin_amdgcn_mfma_f32_32x32x16_bf16(P.wA1[5], g1, C2b, 0, 0, 0);
    C2b = __builtin_amdgcn_mfma_f32_32x32x16_bf16(P.wA1[6], g2, C2b, 0, 0, 0);
    C2b = __builtin_amdgcn_mfma_f32_32x32x16_bf16(P.wA1[7], g3, C2b, 0, 0, 0);

    float pm = 0.f;
#pragma unroll
    for (int r = 0; r < 16; r++) {
        pm = fmaf(fmaxf(C2a[r], 0.f), P.w2v[r >> 2][r & 3], pm);
        pm = fmaf(fmaxf(C2b[r], 0.f), P.w2v[4 + (r >> 2)][r & 3], pm);
    }
    int pi = __builtin_bit_cast(int, pm);
    auto rr = __builtin_amdgcn_permlane32_swap(pi, pi, false, false);
    return __builtin_bit_cast(float, (int)rr[0])
         + __builtin_bit_cast(float, (int)rr[1]) + P.phib2;
}

// ---------- edge kernel A (fallback, R5-proven): f32 x, device atomics to pk0 ----------
__global__ __launch_bounds__(256) void edge_mfma(
    const float* __restrict__ x, const float* __restrict__ pos,
    const int* __restrict__ ei, float* __restrict__ ws,
    const int* __restrict__ flags)
{
    const int lane = threadIdx.x & 63;
    const int c5   = lane & 31;
    const int h5   = lane >> 5;
    const int fidx = flags[0];
    PhiRegs P; load_phi(ws, lane, h5, P);

    __half2* pk = (__half2*)ws;
    const float2* pf = (const float2*)pos;
    const int gw    = blockIdx.x * 4 + (threadIdx.x >> 6);
    const int nwave = gridDim.x * 4;

    for (int tile = gw; tile < NE / 32; tile += nwave) {
        int eg = tile * 32 + c5;
        int src, dst;
        if (fidx) { src = __builtin_nontemporal_load(ei + 2 * eg);
                    dst = __builtin_nontemporal_load(ei + 2 * (NE + eg)); }
        else      { src = __builtin_nontemporal_load(ei + eg);
                    dst = __builtin_nontemporal_load(ei + NE + eg); }
        if ((unsigned)src >= (unsigned)NN) src = 0;
        if ((unsigned)dst >= (unsigned)NN) dst = 0;

        int sel = h5 ? src : dst;
        f4 xa = *(const f4*)(x + sel * 8);
        f4 xb = *(const f4*)(x + sel * 8 + 4);
        float dpx = 0.f, dpy = 0.f, onev = 0.f;
        if (!h5) {
            float2 ps = pf[src], pd = pf[dst];
            dpx = ps.x - pd.x; dpy = ps.y - pd.y; onev = 1.0f;
        }
        uint4 q0;
        q0.x = cvtpk(xa[0], xa[1]); q0.y = cvtpk(xa[2], xa[3]);
        q0.z = cvtpk(xb[0], xb[1]); q0.w = cvtpk(xb[2], xb[3]);
        uint4 q1;
        q1.x = cvtpk(dpx, dpy); q1.y = cvtpk(onev, 0.f); q1.z = 0u; q1.w = 0u;

        float msg = phi_eval(P, __builtin_bit_cast(s8v, q0), __builtin_bit_cast(s8v, q1));

        if (!h5)
            unsafeAtomicAdd(pk + dst, __halves2half2(__float2half(msg), __float2half(1.0f)));
    }
}

// ---------- edge kernel B (R7 + unroll x2): mirror gathers, 2 sub-tiles/iteration ----------
__global__ __launch_bounds__(256) void edge_mir(
    const float* __restrict__ x, const float* __restrict__ pos,
    const int* __restrict__ ei, float* __restrict__ ws,
    const int* __restrict__ flags)
{
    const int lane = threadIdx.x & 63;
    const int c5   = lane & 31;
    const int h5   = lane >> 5;
    const int fidx = flags[0];
    PhiRegs P; load_phi(ws, lane, h5, P);

    __half2* pk = (__half2*)ws;
    const float2* pf = (const float2*)pos;
    const uint4* xbu = (const uint4*)(ws + 212000);

    const int gw    = blockIdx.x * 4 + (threadIdx.x >> 6);
    const int nwave = gridDim.x * 4;
    const int NP    = NE / 64;                   // 25000 pairs, exact

    for (int pt = gw; pt < NP; pt += nwave) {
        // ---- issue ALL loads for both sub-tiles up front ----
        int eg0 = pt * 64 + c5;
        int eg1 = eg0 + 32;
        int s0, d0, s1, d1;
        if (fidx) {
            s0 = __builtin_nontemporal_load(ei + 2 * eg0);
            d0 = __builtin_nontemporal_load(ei + 2 * (NE + eg0));
            s1 = __builtin_nontemporal_load(ei + 2 * eg1);
            d1 = __builtin_nontemporal_load(ei + 2 * (NE + eg1));
        } else {
            s0 = __builtin_nontemporal_load(ei + eg0);
            d0 = __builtin_nontemporal_load(ei + NE + eg0);
            s1 = __builtin_nontemporal_load(ei + eg1);
            d1 = __builtin_nontemporal_load(ei + NE + eg1);
        }
        if ((unsigned)s0 >= (unsigned)NN) s0 = 0;
        if ((unsigned)d0 >= (unsigned)NN) d0 = 0;
        if ((unsigned)s1 >= (unsigned)NN) s1 = 0;
        if ((unsigned)d1 >= (unsigned)NN) d1 = 0;

        int sel0 = h5 ? s0 : d0;
        int sel1 = h5 ? s1 : d1;
        uint4 xv0 = xbu[sel0];
        uint4 xv1 = xbu[sel1];
        float dpx0 = 0.f, dpy0 = 0.f, dpx1 = 0.f, dpy1 = 0.f, onev = 0.f;
        if (!h5) {
            float2 ps0 = pf[s0], pd0 = pf[d0];
            float2 ps1 = pf[s1], pd1 = pf[d1];
            dpx0 = ps0.x - pd0.x; dpy0 = ps0.y - pd0.y;
            dpx1 = ps1.x - pd1.x; dpy1 = ps1.y - pd1.y;
            onev = 1.0f;
        }
        uint4 qa;
        qa.x = cvtpk(dpx0, dpy0); qa.y = cvtpk(onev, 0.f); qa.z = 0u; qa.w = 0u;
        uint4 qb;
        qb.x = cvtpk(dpx1, dpy1); qb.y = cvtpk(onev, 0.f); qb.z = 0u; qb.w = 0u;

        // ---- two independent phi chains ----
        float m0 = phi_eval(P, __builtin_bit_cast(s8v, xv0), __builtin_bit_cast(s8v, qa));
        float m1 = phi_eval(P, __builtin_bit_cast(s8v, xv1), __builtin_bit_cast(s8v, qb));

        // ---- replicated atomics (R7-proven guard) ----
        if ((c5 & 1) == h5) {
            unsafeAtomicAdd(pk + h5 * 100000 + d0,
                            __halves2half2(__float2half(m0), __float2half(1.0f)));
            unsafeAtomicAdd(pk + h5 * 100000 + d1,
                            __halves2half2(__float2half(m1), __float2half(1.0f)));
        }
    }
}

// ---------- node kernel: gamma as 32x32x16 MFMA, sums both pk replicas (R7-proven) ----------
__global__ __launch_bounds__(256) void node_mfma(
    const float* __restrict__ x, float* __restrict__ ws,
    float* __restrict__ out)
{
    const int lane = threadIdx.x & 63;
    const int c5   = lane & 31;
    const int h5   = lane >> 5;

    const unsigned short* fw0 = (const unsigned short*)(ws + 208104);
    const unsigned short* fw1 = (const unsigned short*)(ws + 209128);
    s8v wA0[2], wA1[8];
#pragma unroll
    for (int t = 0; t < 2; t++) wA0[t] = *(const s8v*)(fw0 + (t * 64 + lane) * 8);
#pragma unroll
    for (int f = 0; f < 8; f++) wA1[f] = *(const s8v*)(fw1 + (f * 64 + lane) * 8);

    const float* b1p = ws + 211176;
    const float* w2p = ws + 211240;
    f16v B1a, B1b;
    f4 w2v[8];
#pragma unroll
    for (int g = 0; g < 4; g++) {
        f4 ba = *(const f4*)(b1p + g * 8 + h5 * 4);
        f4 bb = *(const f4*)(b1p + 32 + g * 8 + h5 * 4);
#pragma unroll
        for (int i = 0; i < 4; i++) { B1a[g * 4 + i] = ba[i]; B1b[g * 4 + i] = bb[i]; }
        w2v[g]     = *(const f4*)(w2p + g * 8 + h5 * 4);
        w2v[4 + g] = *(const f4*)(w2p + 32 + g * 8 + h5 * 4);
    }
    const float gamb2 = ws[211304];

    f16v zz;
#pragma unroll
    for (int r = 0; r < 16; r++) zz[r] = 0.f;

    const __half2* pk = (const __half2*)ws;
    const int gw    = blockIdx.x * 4 + (threadIdx.x >> 6);
    const int nwave = gridDim.x * 4;

    for (int tile = gw; tile < NN / 32; tile += nwave) {
        int n = tile * 32 + c5;
        f4 xa = {0.f, 0.f, 0.f, 0.f}, xb = {0.f, 0.f, 0.f, 0.f};
        float aggv = 0.f;
        if (!h5) {
            xa = *(const f4*)(x + n * 8);
            xb = *(const f4*)(x + n * 8 + 4);
        } else {
            __half2 pc0 = pk[n];
            __half2 pc1 = pk[n + 100000];
            float s  = __half2float(pc0.x) + __half2float(pc1.x);
            float ct = __half2float(pc0.y) + __half2float(pc1.y);
            aggv = s / fmaxf(ct, 1.0f);
        }
        uint4 q0;
        q0.x = h5 ? cvtpk(aggv, 1.0f) : cvtpk(xa[0], xa[1]);
        q0.y = h5 ? 0u : cvtpk(xa[2], xa[3]);
        q0.z = h5 ? 0u : cvtpk(xb[0], xb[1]);
        q0.w = h5 ? 0u : cvtpk(xb[2], xb[3]);
        s8v bf0 = __builtin_bit_cast(s8v, q0);

        f16v C1 = __builtin_amdgcn_mfma_f32_32x32x16_bf16(wA0[0], bf0, zz, 0, 0, 0);
        s8v g0 = interleave8<0>(C1);
        s8v g1 = interleave8<8>(C1);
        C1 = __builtin_amdgcn_mfma_f32_32x32x16_bf16(wA0[1], bf0, zz, 0, 0, 0);
        s8v g2 = interleave8<0>(C1);
        s8v g3 = interleave8<8>(C1);

        f16v C2a = __builtin_amdgcn_mfma_f32_32x32x16_bf16(wA1[0], g0, B1a, 0, 0, 0);
        C2a = __builtin_amdgcn_mfma_f32_32x32x16_bf16(wA1[1], g1, C2a, 0, 0, 0);
        C2a = __builtin_amdgcn_mfma_f32_32x32x16_bf16(wA1[2], g2, C2a, 0, 0, 0);
        C2a = __builtin_amdgcn_mfma_f32_32x32x16_bf16(wA1[3], g3, C2a, 0, 0, 0);
        f16v C2b = __builtin_amdgcn_mfma_f32_32x32x16_bf16(wA1[4], g0, B1b, 0, 0, 0);
        C2b = __builtin_amdgcn_mfma_f32_32x32x16_bf16(wA1[5], g1, C2b, 0, 0, 0);
        C2b = __builtin_amdgcn_mfma_f32_32x32x16_bf16(wA1[6], g2, C2b, 0, 0, 0);
        C2b = __builtin_amdgcn_mfma_f32_32x32x16_bf16(wA1[7], g3, C2b, 0, 0, 0);

        float pm = 0.f;
#pragma unroll
        for (int r = 0; r < 16; r++) {
            pm = fmaf(fmaxf(C2a[r], 0.f), w2v[r >> 2][r & 3], pm);
            pm = fmaf(fmaxf(C2b[r], 0.f), w2v[4 + (r >> 2)][r & 3], pm);
        }
        int pi = __builtin_bit_cast(int, pm);
        auto rr = __builtin_amdgcn_permlane32_swap(pi, pi, false, false);
        float tot = __builtin_bit_cast(float, (int)rr[0])
                  + __builtin_bit_cast(float, (int)rr[1]);

        if (!h5)
            out[n] = xb[3] + tot + gamb2;
    }
}

extern "C" void kernel_launch(void* const* d_in, const int* in_sizes, int n_in,
                              void* d_out, int out_size, void* d_ws, size_t ws_size,
                              hipStream_t stream) {
    const float* x   = (const float*)d_in[0];
    const float* pos = (const float*)d_in[1];
    const int*   ei  = (const int*)d_in[2];

    float* ws    = (float*)d_ws;
    int*   flags = (int*)(ws + 208100);

    const bool big = ws_size >= 612000ull * 4ull;   // room for bf16-x mirror

    prep<<<70, 256, 0, stream>>>(
        (const float*)d_in[3],  (const float*)d_in[4],  (const float*)d_in[5],
        (const float*)d_in[6],  (const float*)d_in[7],  (const float*)d_in[8],
        (const float*)d_in[9],  (const float*)d_in[10], (const float*)d_in[11],
        (const float*)d_in[12], (const float*)d_in[13], (const float*)d_in[14],
        ei, x, ws, big ? 1 : 0);

    if (big) edge_mir<<<2048, 256, 0, stream>>>(x, pos, ei, ws, flags);
    else     edge_mfma<<<2048, 256, 0, stream>>>(x, pos, ei, ws, flags);

    node_mfma<<<1024, 256, 0, stream>>>(x, ws, (float*)d_out);
}

// Round 10
// 187.031 us; speedup vs baseline: 1.0196x; 1.0026x over previous
//
#include <hip/hip_runtime.h>
#include <hip/hip_fp16.h>

#define NN 100000
#define NE 1600000

typedef short s8v  __attribute__((ext_vector_type(8)));    // 8 bf16 = 4 VGPRs
typedef float f4   __attribute__((ext_vector_type(4)));
typedef float f16v __attribute__((ext_vector_type(16)));   // 32x32 MFMA accumulator

// ---------- dtype helpers ----------
__device__ __forceinline__ unsigned short f2b(float f) {   // fp32 -> bf16 RNE (prep only)
    unsigned int u = __float_as_uint(f);
    return (unsigned short)((u + 0x7fffu + ((u >> 16) & 1u)) >> 16);
}
__device__ __forceinline__ unsigned int cvtpk(float lo, float hi) {  // 2xf32 -> packed bf16 (RNE)
    unsigned int r;
    asm("v_cvt_pk_bf16_f32 %0, %1, %2" : "=v"(r) : "v"(lo), "v"(hi));
    return r;
}

// Inter-layer exchange for 32x32x16 chains (proven R2/R5/R6/R7/R9).
template<int BASE>
__device__ __forceinline__ s8v interleave8(f16v C) {
    unsigned a0 = cvtpk(fmaxf(C[BASE + 0], 0.f), fmaxf(C[BASE + 1], 0.f));
    unsigned a1 = cvtpk(fmaxf(C[BASE + 2], 0.f), fmaxf(C[BASE + 3], 0.f));
    unsigned b0 = cvtpk(fmaxf(C[BASE + 4], 0.f), fmaxf(C[BASE + 5], 0.f));
    unsigned b1 = cvtpk(fmaxf(C[BASE + 6], 0.f), fmaxf(C[BASE + 7], 0.f));
    auto r0 = __builtin_amdgcn_permlane32_swap((int)a0, (int)b0, false, false);
    auto r1 = __builtin_amdgcn_permlane32_swap((int)a1, (int)b1, false, false);
    uint4 q;
    q.x = (unsigned)r0[0];
    q.y = (unsigned)r1[0];
    q.z = (unsigned)r0[1];
    q.w = (unsigned)r1[1];
    return __builtin_bit_cast(s8v, q);
}

// ---------- workspace layout (float index) ----------
// pk replica0 @0      [100000 __half2] | pk replica1 @100000 [100000 __half2]
// phi b1 @204868[64] | phi w2 @204932[64] | phi b2 @204996[1]
// phi fragW0 @205000 (2048 bf16) | phi fragW1 @206024 (4096 bf16)   <- contiguous 12KB
// flags @208100 | gam fragW0 @208104 (1024 bf16) | gam fragW1 @209128 (4096 bf16)
// gam b1 @211176[64] | gam w2 @211240[64] | gam b2 @211304[1]
// x-bf16 mirror @212000 (NN uint4 = 400000 floats, ends 612000) -- only if ws big

__global__ __launch_bounds__(256) void prep(
    const float* __restrict__ pW0, const float* __restrict__ pb0,
    const float* __restrict__ pW1, const float* __restrict__ pb1,
    const float* __restrict__ pW2, const float* __restrict__ pb2,
    const float* __restrict__ gW0, const float* __restrict__ gb0,
    const float* __restrict__ gW1, const float* __restrict__ gb1,
    const float* __restrict__ gW2, const float* __restrict__ gb2,
    const int* __restrict__ ei, const float* __restrict__ xin,
    float* __restrict__ ws, int do_x)
{
    // ---- zero BOTH pk replicas (all blocks) ----
    for (int i = blockIdx.x * 256 + threadIdx.x; i < 200000; i += gridDim.x * 256)
        ws[i] = 0.0f;

    // ---- pack x -> bf16 mirror (all blocks; same RNE as the in-loop cvtpk path) ----
    if (do_x) {
        uint4* xbu = (uint4*)(ws + 212000);
        for (int i = blockIdx.x * 256 + threadIdx.x; i < NN; i += gridDim.x * 256) {
            f4 a = *(const f4*)(xin + i * 8);
            f4 b = *(const f4*)(xin + i * 8 + 4);
            uint4 o;
            o.x = cvtpk(a[0], a[1]); o.y = cvtpk(a[2], a[3]);
            o.z = cvtpk(b[0], b[1]); o.w = cvtpk(b[2], b[3]);
            xbu[i] = o;
        }
    }

    // ---- sniff edge-index width (last block only) ----
    if (blockIdx.x == gridDim.x - 1) {
        __shared__ int s_zero;
        if (threadIdx.x == 0) s_zero = 0;
        __syncthreads();
        int zero = 0;
        for (int i = threadIdx.x; i < 1024; i += 256)
            if (ei[2 * i + 1] == 0) zero++;      // int64 high words all zero
        atomicAdd(&s_zero, zero);
        __syncthreads();
        if (threadIdx.x == 0) ((int*)(ws + 208100))[0] = (s_zero > 512) ? 1 : 0;
        return;
    }

    // ---- weight staging ----
    int t = blockIdx.x * 256 + threadIdx.x;
    if (t < 64)        ws[204868 + t] = pb1[t];
    else if (t < 128)  ws[204932 + t - 64] = pW2[t - 64];
    else if (t == 128) ws[204996] = pb2[0];
    else if (t >= 256 && t < 2304) {            // phi fragW0 (2048): bias folded at k=18
        int fe = t - 256;
        int j = fe & 7, ln = (fe >> 3) & 63, ts = fe >> 9;
        int tt = ts >> 1, s = ts & 1;
        int k = s * 16 + (ln >> 5) * 8 + j;
        int n = tt * 32 + (ln & 31);
        float v = (k < 18) ? pW0[k * 64 + n] : ((k == 18) ? pb0[n] : 0.0f);
        ((unsigned short*)(ws + 205000))[fe] = f2b(v);
    }
    else if (t >= 2304 && t < 6400) {           // phi fragW1 (4096)
        int fe = t - 2304;
        int j = fe & 7, ln = (fe >> 3) & 63, f = fe >> 9;
        int tt = f >> 2, s2 = f & 3;
        int k = s2 * 16 + (ln >> 5) * 8 + j;
        int n = tt * 32 + (ln & 31);
        ((unsigned short*)(ws + 206024))[fe] = f2b(pW1[k * 64 + n]);
    }
    else if (t >= 6400 && t < 7424) {           // gam fragW0 (1024): bias folded at k=9
        int fe = t - 6400;
        int j = fe & 7, ln = (fe >> 3) & 63, tt = fe >> 9;
        int k = (ln >> 5) * 8 + j;
        int n = tt * 32 + (ln & 31);
        float v = (k < 9) ? gW0[k * 64 + n] : ((k == 9) ? gb0[n] : 0.0f);
        ((unsigned short*)(ws + 208104))[fe] = f2b(v);
    }
    else if (t >= 7424 && t < 11520) {          // gam fragW1 (4096)
        int fe = t - 7424;
        int j = fe & 7, ln = (fe >> 3) & 63, f = fe >> 9;
        int tt = f >> 2, s2 = f & 3;
        int k = s2 * 16 + (ln >> 5) * 8 + j;
        int n = tt * 32 + (ln & 31);
        ((unsigned short*)(ws + 209128))[fe] = f2b(gW1[k * 64 + n]);
    }
    else if (t >= 11520 && t < 11584) ws[211176 + t - 11520] = gb1[t - 11520];
    else if (t >= 11584 && t < 11648) ws[211240 + t - 11584] = gW2[t - 11584];
    else if (t == 11648) ws[211304] = gb2[0];
}

// ---------- edge kernel (LDS weights, occupancy-targeted): 32 edges/wave ----------
// __launch_bounds__(256, 4): cap 128 VGPR/wave -> >=4 waves/SIMD. Weights live in LDS,
// re-read per tile (hideable); only B1a/B1b + working set stay in registers.
__global__ __launch_bounds__(256, 4) void edge_lds(
    const float* __restrict__ x, const float* __restrict__ pos,
    const int* __restrict__ ei, float* __restrict__ ws,
    const int* __restrict__ flags)
{
    __shared__ __align__(16) unsigned short lwA[6144];   // wA0 (2048) ++ wA1 (4096), 12KB
    __shared__ float lb1[64];
    __shared__ float lw2[64];

    const int tid  = threadIdx.x;
    const int lane = tid & 63;
    const int c5   = lane & 31;
    const int h5   = lane >> 5;
    const int fidx = flags[0];

    // ---- stage weights global -> LDS (once per block) ----
    {
        const uint4* srcv = (const uint4*)(ws + 205000);   // 12KB contiguous frags
        uint4* dstv = (uint4*)lwA;
#pragma unroll
        for (int i = tid; i < 768; i += 256) dstv[i] = srcv[i];
        if (tid < 64)               lb1[tid] = ws[204868 + tid];
        else if (tid < 128)         lw2[tid - 64] = ws[204932 + tid - 64];
    }
    __syncthreads();

    // persistent registers: layer-2 bias as accumulator init (32 VGPR) + phib2
    f16v B1a, B1b;
#pragma unroll
    for (int g = 0; g < 4; g++) {
        f4 ba = *(const f4*)(lb1 + g * 8 + h5 * 4);
        f4 bb = *(const f4*)(lb1 + 32 + g * 8 + h5 * 4);
#pragma unroll
        for (int i = 0; i < 4; i++) { B1a[g * 4 + i] = ba[i]; B1b[g * 4 + i] = bb[i]; }
    }
    const float phib2 = ws[204996];

    __half2* pk = (__half2*)ws;
    const float2* pf = (const float2*)pos;
    const uint4* xbu = (const uint4*)(ws + 212000);

    const int gw    = blockIdx.x * 4 + (tid >> 6);
    const int nwave = gridDim.x * 4;

    for (int tile = gw; tile < NE / 32; tile += nwave) {
        int eg = tile * 32 + c5;
        int src, dst;
        if (fidx) { src = __builtin_nontemporal_load(ei + 2 * eg);
                    dst = __builtin_nontemporal_load(ei + 2 * (NE + eg)); }
        else      { src = __builtin_nontemporal_load(ei + eg);
                    dst = __builtin_nontemporal_load(ei + NE + eg); }
        if ((unsigned)src >= (unsigned)NN) src = 0;
        if ((unsigned)dst >= (unsigned)NN) dst = 0;

        // half-wave role split: h5=0 -> x[dst] + pos; h5=1 -> x[src]. ONE 16B gather.
        int sel = h5 ? src : dst;
        uint4 xv = xbu[sel];
        float dpx = 0.f, dpy = 0.f, onev = 0.f;
        if (!h5) {
            float2 ps = pf[src], pd = pf[dst];
            dpx = ps.x - pd.x; dpy = ps.y - pd.y; onev = 1.0f;
        }
        s8v bf0 = __builtin_bit_cast(s8v, xv);
        uint4 q1;
        q1.x = cvtpk(dpx, dpy); q1.y = cvtpk(onev, 0.f); q1.z = 0u; q1.w = 0u;
        s8v bf1 = __builtin_bit_cast(s8v, q1);

        f16v zz;
#pragma unroll
        for (int r = 0; r < 16; r++) zz[r] = 0.f;

        // layer 1: A-fragments from LDS
        f16v C1 = __builtin_amdgcn_mfma_f32_32x32x16_bf16(
            *(const s8v*)(lwA + (0 * 64 + lane) * 8), bf0, zz, 0, 0, 0);
        C1 = __builtin_amdgcn_mfma_f32_32x32x16_bf16(
            *(const s8v*)(lwA + (1 * 64 + lane) * 8), bf1, C1, 0, 0, 0);
        s8v g0 = interleave8<0>(C1);
        s8v g1 = interleave8<8>(C1);
        C1 = __builtin_amdgcn_mfma_f32_32x32x16_bf16(
            *(const s8v*)(lwA + (2 * 64 + lane) * 8), bf0, zz, 0, 0, 0);
        C1 = __builtin_amdgcn_mfma_f32_32x32x16_bf16(
            *(const s8v*)(lwA + (3 * 64 + lane) * 8), bf1, C1, 0, 0, 0);
        s8v g2 = interleave8<0>(C1);
        s8v g3 = interleave8<8>(C1);

        // layer 2: K=64 = 4x16, accumulator starts at b1 (A-frags from LDS)
        const unsigned short* lw1 = lwA + 2048;
        f16v C2a = __builtin_amdgcn_mfma_f32_32x32x16_bf16(
            *(const s8v*)(lw1 + (0 * 64 + lane) * 8), g0, B1a, 0, 0, 0);
        C2a = __builtin_amdgcn_mfma_f32_32x32x16_bf16(
            *(const s8v*)(lw1 + (1 * 64 + lane) * 8), g1, C2a, 0, 0, 0);
        C2a = __builtin_amdgcn_mfma_f32_32x32x16_bf16(
            *(const s8v*)(lw1 + (2 * 64 + lane) * 8), g2, C2a, 0, 0, 0);
        C2a = __builtin_amdgcn_mfma_f32_32x32x16_bf16(
            *(const s8v*)(lw1 + (3 * 64 + lane) * 8), g3, C2a, 0, 0, 0);
        f16v C2b = __builtin_amdgcn_mfma_f32_32x32x16_bf16(
            *(const s8v*)(lw1 + (4 * 64 + lane) * 8), g0, B1b, 0, 0, 0);
        C2b = __builtin_amdgcn_mfma_f32_32x32x16_bf16(
            *(const s8v*)(lw1 + (5 * 64 + lane) * 8), g1, C2b, 0, 0, 0);
        C2b = __builtin_amdgcn_mfma_f32_32x32x16_bf16(
            *(const s8v*)(lw1 + (6 * 64 + lane) * 8), g2, C2b, 0, 0, 0);
        C2b = __builtin_amdgcn_mfma_f32_32x32x16_bf16(
            *(const s8v*)(lw1 + (7 * 64 + lane) * 8), g3, C2b, 0, 0, 0);

        // epilogue: w2 from LDS per tile
        float pm = 0.f;
#pragma unroll
        for (int g = 0; g < 4; g++) {
            f4 wa = *(const f4*)(lw2 + g * 8 + h5 * 4);
            f4 wb = *(const f4*)(lw2 + 32 + g * 8 + h5 * 4);
#pragma unroll
            for (int i = 0; i < 4; i++) {
                pm = fmaf(fmaxf(C2a[g * 4 + i], 0.f), wa[i], pm);
                pm = fmaf(fmaxf(C2b[g * 4 + i], 0.f), wb[i], pm);
            }
        }
        int pi = __builtin_bit_cast(int, pm);
        auto rr = __builtin_amdgcn_permlane32_swap(pi, pi, false, false);
        float msg = __builtin_bit_cast(float, (int)rr[0])
                  + __builtin_bit_cast(float, (int)rr[1]) + phib2;

        // R7-proven replicated atomic: even edges -> replica0 (h5=0), odd -> replica1 (h5=1)
        if ((c5 & 1) == h5)
            unsafeAtomicAdd(pk + h5 * 100000 + dst,
                            __halves2half2(__float2half(msg), __float2half(1.0f)));
    }
}

// ---------- edge kernel fallback (R5-proven, f32 x, device atomics to pk0) ----------
__global__ __launch_bounds__(256) void edge_mfma(
    const float* __restrict__ x, const float* __restrict__ pos,
    const int* __restrict__ ei, float* __restrict__ ws,
    const int* __restrict__ flags)
{
    const int lane = threadIdx.x & 63;
    const int c5   = lane & 31;
    const int h5   = lane >> 5;
    const int fidx = flags[0];

    const unsigned short* fw0 = (const unsigned short*)(ws + 205000);
    const unsigned short* fw1 = (const unsigned short*)(ws + 206024);
    s8v wA0[4], wA1[8];
#pragma unroll
    for (int t = 0; t < 4; t++) wA0[t] = *(const s8v*)(fw0 + (t * 64 + lane) * 8);
#pragma unroll
    for (int f = 0; f < 8; f++) wA1[f] = *(const s8v*)(fw1 + (f * 64 + lane) * 8);

    const float* b1p = ws + 204868;
    const float* w2p = ws + 204932;
    f16v B1a, B1b;
    f4 w2v[8];
#pragma unroll
    for (int g = 0; g < 4; g++) {
        f4 ba = *(const f4*)(b1p + g * 8 + h5 * 4);
        f4 bb = *(const f4*)(b1p + 32 + g * 8 + h5 * 4);
#pragma unroll
        for (int i = 0; i < 4; i++) { B1a[g * 4 + i] = ba[i]; B1b[g * 4 + i] = bb[i]; }
        w2v[g]     = *(const f4*)(w2p + g * 8 + h5 * 4);
        w2v[4 + g] = *(const f4*)(w2p + 32 + g * 8 + h5 * 4);
    }
    const float phib2 = ws[204996];

    f16v zz;
#pragma unroll
    for (int r = 0; r < 16; r++) zz[r] = 0.f;

    __half2* pk = (__half2*)ws;
    const float2* pf = (const float2*)pos;
    const int gw    = blockIdx.x * 4 + (threadIdx.x >> 6);
    const int nwave = gridDim.x * 4;

    for (int tile = gw; tile < NE / 32; tile += nwave) {
        int eg = tile * 32 + c5;
        int src, dst;
        if (fidx) { src = __builtin_nontemporal_load(ei + 2 * eg);
                    dst = __builtin_nontemporal_load(ei + 2 * (NE + eg)); }
        else      { src = __builtin_nontemporal_load(ei + eg);
                    dst = __builtin_nontemporal_load(ei + NE + eg); }
        if ((unsigned)src >= (unsigned)NN) src = 0;
        if ((unsigned)dst >= (unsigned)NN) dst = 0;

        int sel = h5 ? src : dst;
        f4 xa = *(const f4*)(x + sel * 8);
        f4 xb = *(const f4*)(x + sel * 8 + 4);
        float dpx = 0.f, dpy = 0.f, onev = 0.f;
        if (!h5) {
            float2 ps = pf[src], pd = pf[dst];
            dpx = ps.x - pd.x; dpy = ps.y - pd.y; onev = 1.0f;
        }
        uint4 q0;
        q0.x = cvtpk(xa[0], xa[1]); q0.y = cvtpk(xa[2], xa[3]);
        q0.z = cvtpk(xb[0], xb[1]); q0.w = cvtpk(xb[2], xb[3]);
        s8v bf0 = __builtin_bit_cast(s8v, q0);
        uint4 q1;
        q1.x = cvtpk(dpx, dpy); q1.y = cvtpk(onev, 0.f); q1.z = 0u; q1.w = 0u;
        s8v bf1 = __builtin_bit_cast(s8v, q1);

        f16v C1 = __builtin_amdgcn_mfma_f32_32x32x16_bf16(wA0[0], bf0, zz, 0, 0, 0);
        C1 = __builtin_amdgcn_mfma_f32_32x32x16_bf16(wA0[1], bf1, C1, 0, 0, 0);
        s8v g0 = interleave8<0>(C1);
        s8v g1 = interleave8<8>(C1);
        C1 = __builtin_amdgcn_mfma_f32_32x32x16_bf16(wA0[2], bf0, zz, 0, 0, 0);
        C1 = __builtin_amdgcn_mfma_f32_32x32x16_bf16(wA0[3], bf1, C1, 0, 0, 0);
        s8v g2 = interleave8<0>(C1);
        s8v g3 = interleave8<8>(C1);

        f16v C2a = __builtin_amdgcn_mfma_f32_32x32x16_bf16(wA1[0], g0, B1a, 0, 0, 0);
        C2a = __builtin_amdgcn_mfma_f32_32x32x16_bf16(wA1[1], g1, C2a, 0, 0, 0);
        C2a = __builtin_amdgcn_mfma_f32_32x32x16_bf16(wA1[2], g2, C2a, 0, 0, 0);
        C2a = __builtin_amdgcn_mfma_f32_32x32x16_bf16(wA1[3], g3, C2a, 0, 0, 0);
        f16v C2b = __builtin_amdgcn_mfma_f32_32x32x16_bf16(wA1[4], g0, B1b, 0, 0, 0);
        C2b = __builtin_amdgcn_mfma_f32_32x32x16_bf16(wA1[5], g1, C2b, 0, 0, 0);
        C2b = __builtin_amdgcn_mfma_f32_32x32x16_bf16(wA1[6], g2, C2b, 0, 0, 0);
        C2b = __builtin_amdgcn_mfma_f32_32x32x16_bf16(wA1[7], g3, C2b, 0, 0, 0);

        float pm = 0.f;
#pragma unroll
        for (int r = 0; r < 16; r++) {
            pm = fmaf(fmaxf(C2a[r], 0.f), w2v[r >> 2][r & 3], pm);
            pm = fmaf(fmaxf(C2b[r], 0.f), w2v[4 + (r >> 2)][r & 3], pm);
        }
        int pi = __builtin_bit_cast(int, pm);
        auto rr = __builtin_amdgcn_permlane32_swap(pi, pi, false, false);
        float msg = __builtin_bit_cast(float, (int)rr[0])
                  + __builtin_bit_cast(float, (int)rr[1]) + phib2;

        if (!h5)
            unsafeAtomicAdd(pk + dst, __halves2half2(__float2half(msg), __float2half(1.0f)));
    }
}

// ---------- node kernel: gamma as 32x32x16 MFMA, sums both pk replicas (R7-proven) ----------
__global__ __launch_bounds__(256) void node_mfma(
    const float* __restrict__ x, float* __restrict__ ws,
    float* __restrict__ out)
{
    const int lane = threadIdx.x & 63;
    const int c5   = lane & 31;
    const int h5   = lane >> 5;

    const unsigned short* fw0 = (const unsigned short*)(ws + 208104);
    const unsigned short* fw1 = (const unsigned short*)(ws + 209128);
    s8v wA0[2], wA1[8];
#pragma unroll
    for (int t = 0; t < 2; t++) wA0[t] = *(const s8v*)(fw0 + (t * 64 + lane) * 8);
#pragma unroll
    for (int f = 0; f < 8; f++) wA1[f] = *(const s8v*)(fw1 + (f * 64 + lane) * 8);

    const float* b1p = ws + 211176;
    const float* w2p = ws + 211240;
    f16v B1a, B1b;
    f4 w2v[8];
#pragma unroll
    for (int g = 0; g < 4; g++) {
        f4 ba = *(const f4*)(b1p + g * 8 + h5 * 4);
        f4 bb = *(const f4*)(b1p + 32 + g * 8 + h5 * 4);
#pragma unroll
        for (int i = 0; i < 4; i++) { B1a[g * 4 + i] = ba[i]; B1b[g * 4 + i] = bb[i]; }
        w2v[g]     = *(const f4*)(w2p + g * 8 + h5 * 4);
        w2v[4 + g] = *(const f4*)(w2p + 32 + g * 8 + h5 * 4);
    }
    const float gamb2 = ws[211304];

    f16v zz;
#pragma unroll
    for (int r = 0; r < 16; r++) zz[r] = 0.f;

    const __half2* pk = (const __half2*)ws;
    const int gw    = blockIdx.x * 4 + (threadIdx.x >> 6);
    const int nwave = gridDim.x * 4;

    for (int tile = gw; tile < NN / 32; tile += nwave) {
        int n = tile * 32 + c5;
        f4 xa = {0.f, 0.f, 0.f, 0.f}, xb = {0.f, 0.f, 0.f, 0.f};
        float aggv = 0.f;
        if (!h5) {
            xa = *(const f4*)(x + n * 8);
            xb = *(const f4*)(x + n * 8 + 4);
        } else {
            __half2 pc0 = pk[n];
            __half2 pc1 = pk[n + 100000];
            float s  = __half2float(pc0.x) + __half2float(pc1.x);
            float ct = __half2float(pc0.y) + __half2float(pc1.y);
            aggv = s / fmaxf(ct, 1.0f);
        }
        uint4 q0;
        q0.x = h5 ? cvtpk(aggv, 1.0f) : cvtpk(xa[0], xa[1]);
        q0.y = h5 ? 0u : cvtpk(xa[2], xa[3]);
        q0.z = h5 ? 0u : cvtpk(xb[0], xb[1]);
        q0.w = h5 ? 0u : cvtpk(xb[2], xb[3]);
        s8v bf0 = __builtin_bit_cast(s8v, q0);

        f16v C1 = __builtin_amdgcn_mfma_f32_32x32x16_bf16(wA0[0], bf0, zz, 0, 0, 0);
        s8v g0 = interleave8<0>(C1);
        s8v g1 = interleave8<8>(C1);
        C1 = __builtin_amdgcn_mfma_f32_32x32x16_bf16(wA0[1], bf0, zz, 0, 0, 0);
        s8v g2 = interleave8<0>(C1);
        s8v g3 = interleave8<8>(C1);

        f16v C2a = __builtin_amdgcn_mfma_f32_32x32x16_bf16(wA1[0], g0, B1a, 0, 0, 0);
        C2a = __builtin_amdgcn_mfma_f32_32x32x16_bf16(wA1[1], g1, C2a, 0, 0, 0);
        C2a = __builtin_amdgcn_mfma_f32_32x32x16_bf16(wA1[2], g2, C2a, 0, 0, 0);
        C2a = __builtin_amdgcn_mfma_f32_32x32x16_bf16(wA1[3], g3, C2a, 0, 0, 0);
        f16v C2b = __builtin_amdgcn_mfma_f32_32x32x16_bf16(wA1[4], g0, B1b, 0, 0, 0);
        C2b = __builtin_amdgcn_mfma_f32_32x32x16_bf16(wA1[5], g1, C2b, 0, 0, 0);
        C2b = __builtin_amdgcn_mfma_f32_32x32x16_bf16(wA1[6], g2, C2b, 0, 0, 0);
        C2b = __builtin_amdgcn_mfma_f32_32x32x16_bf16(wA1[7], g3, C2b, 0, 0, 0);

        float pm = 0.f;
#pragma unroll
        for (int r = 0; r < 16; r++) {
            pm = fmaf(fmaxf(C2a[r], 0.f), w2v[r >> 2][r & 3], pm);
            pm = fmaf(fmaxf(C2b[r], 0.f), w2v[4 + (r >> 2)][r & 3], pm);
        }
        int pi = __builtin_bit_cast(int, pm);
        auto rr = __builtin_amdgcn_permlane32_swap(pi, pi, false, false);
        float tot = __builtin_bit_cast(float, (int)rr[0])
                  + __builtin_bit_cast(float, (int)rr[1]);

        if (!h5)
            out[n] = xb[3] + tot + gamb2;
    }
}

extern "C" void kernel_launch(void* const* d_in, const int* in_sizes, int n_in,
                              void* d_out, int out_size, void* d_ws, size_t ws_size,
                              hipStream_t stream) {
    const float* x   = (const float*)d_in[0];
    const float* pos = (const float*)d_in[1];
    const int*   ei  = (const int*)d_in[2];

    float* ws    = (float*)d_ws;
    int*   flags = (int*)(ws + 208100);

    const bool big = ws_size >= 612000ull * 4ull;   // room for bf16-x mirror

    prep<<<70, 256, 0, stream>>>(
        (const float*)d_in[3],  (const float*)d_in[4],  (const float*)d_in[5],
        (const float*)d_in[6],  (const float*)d_in[7],  (const float*)d_in[8],
        (const float*)d_in[9],  (const float*)d_in[10], (const float*)d_in[11],
        (const float*)d_in[12], (const float*)d_in[13], (const float*)d_in[14],
        ei, x, ws, big ? 1 : 0);

    if (big) edge_lds<<<2048, 256, 0, stream>>>(x, pos, ei, ws, flags);
    else     edge_mfma<<<2048, 256, 0, stream>>>(x, pos, ei, ws, flags);

    node_mfma<<<1024, 256, 0, stream>>>(x, ws, (float*)d_out);
}